// Round 1
// baseline (460.319 us; speedup 1.0000x reference)
//
#include <hip/hip_runtime.h>
#include <math.h>

#define TPB 256

// out = 0.25 * K^T * silu(K * x * K^T) * K   per 64x64 image, K[m][i] = k((m-2i) mod 128)
// k = ideal half-band (sinc) kernel derived from the reference's FFT zero-pad + Nyquist split.
//
// LDS pool (floats). Total 34,432 floats = 137,728 B (<= 160 KiB gfx950 WG limit, 1 WG/CU).
//  R1 [0      .. 16,896): aBuf[128][132] (phases B..C) | xsT[64][68] (phase A alias)
//  R2 [16,896 .. 25,600): Km  [128][68]  (phases A..B) | KmT[64][132] (phases C..D alias)
//  R3 [25,600 .. 34,304): t1  [128][68]  (phases A..B) | t2T[64][132] (phases C..D alias)
//  k1d [34,304 .. 34,432)
// Row strides 68/132 floats: 16B-aligned (float4 LDS reads) and stride%32==4 rotates banks.

__device__ __forceinline__ float dot4(float4 a, float4 b) {
  return a.x * b.x + a.y * b.y + a.z * b.z + a.w * b.w;
}

__global__ __launch_bounds__(TPB) void warped_kernel(const float* __restrict__ xin,
                                                     float* __restrict__ outp) {
  __shared__ float lds[34432];
  float* const aBuf = lds;           // [128][132]
  float* const xsT  = lds;           // [64][68]   alias (dead after phase A)
  float* const Km   = lds + 16896;   // [128][68]
  float* const KmT  = lds + 16896;   // [64][132]  alias (written after B)
  float* const t1   = lds + 25600;   // [128][68]
  float* const t2T  = lds + 25600;   // [64][132]  alias (written in C, t1 dead)
  float* const k1d  = lds + 34304;   // [128]

  const int tid = threadIdx.x;
  const float* __restrict__ x = xin + (size_t)blockIdx.x * 4096;
  float* __restrict__ out     = outp + (size_t)blockIdx.x * 4096;

  // ---- 1D half-band kernel: k(d) = (1/64)[1 + 2*sum_{f=1..31} cos(pi f d/64) + cos(pi d/2)]
  if (tid < 128) {
    const int d = tid;
    float s = 1.0f + ((d & 1) ? 0.0f : ((d & 2) ? -1.0f : 1.0f));  // cos(pi*d/2) exact
    for (int f = 1; f <= 31; ++f) {
      int r = (f * d) & 127;  // exact periodic arg reduction
      s += 2.0f * cosf((float)r * 0.04908738521234052f /* pi/64 */);
    }
    k1d[d] = s * (1.0f / 64.0f);
  }
  __syncthreads();

  // ---- Km[m][i] = k(m-2i);  xsT[j][i] = x[i][j]
  for (int idx = tid; idx < 128 * 64; idx += TPB) {
    int m = idx >> 6, i = idx & 63;
    Km[m * 68 + i] = k1d[(m - 2 * i) & 127];
  }
  for (int idx = tid; idx < 1024; idx += TPB) {
    float4 v = ((const float4*)x)[idx];
    int i = idx >> 4, j0 = (idx & 15) * 4;
    xsT[(j0 + 0) * 68 + i] = v.x;
    xsT[(j0 + 1) * 68 + i] = v.y;
    xsT[(j0 + 2) * 68 + i] = v.z;
    xsT[(j0 + 3) * 68 + i] = v.w;
  }
  __syncthreads();

  // ---- Stage A: t1[m][j] = dot(Km_row[m], xsT_row[j]), len 64.  Tiles 8m x 4j.
  {
    const int tm = tid >> 4, tj = tid & 15;  // m = tm*8.., j = tj*4..
    float acc[8][4];
#pragma unroll
    for (int r = 0; r < 8; ++r)
#pragma unroll
      for (int s = 0; s < 4; ++s) acc[r][s] = 0.0f;
    const float* Kr = Km + tm * 8 * 68;
    const float* Xr = xsT + tj * 4 * 68;
    for (int i = 0; i < 64; i += 4) {
      float4 kv[8], xv[4];
#pragma unroll
      for (int r = 0; r < 8; ++r) kv[r] = *(const float4*)(Kr + r * 68 + i);
#pragma unroll
      for (int s = 0; s < 4; ++s) xv[s] = *(const float4*)(Xr + s * 68 + i);
#pragma unroll
      for (int r = 0; r < 8; ++r)
#pragma unroll
        for (int s = 0; s < 4; ++s) acc[r][s] += dot4(kv[r], xv[s]);
    }
#pragma unroll
    for (int r = 0; r < 8; ++r)
#pragma unroll
      for (int s = 0; s < 4; ++s) t1[(tm * 8 + r) * 68 + tj * 4 + s] = acc[r][s];
  }
  __syncthreads();

  // ---- Stage B: aBuf[m][n] = silu(dot(t1_row[m], Km_row[n])), len 64.  Tiles 8m x 8n.
  // (writes into xsT's region — xsT dead after A)
  {
    const int tm = tid >> 4, tn = tid & 15;  // m = tm*8.., n = tn*8..
    float acc[8][8];
#pragma unroll
    for (int r = 0; r < 8; ++r)
#pragma unroll
      for (int s = 0; s < 8; ++s) acc[r][s] = 0.0f;
    const float* Ar = t1 + tm * 8 * 68;
    const float* Br = Km + tn * 8 * 68;
    for (int j = 0; j < 64; j += 4) {
      float4 av[8], bv[8];
#pragma unroll
      for (int r = 0; r < 8; ++r) av[r] = *(const float4*)(Ar + r * 68 + j);
#pragma unroll
      for (int s = 0; s < 8; ++s) bv[s] = *(const float4*)(Br + s * 68 + j);
#pragma unroll
      for (int r = 0; r < 8; ++r)
#pragma unroll
        for (int s = 0; s < 8; ++s) acc[r][s] += dot4(av[r], bv[s]);
    }
#pragma unroll
    for (int r = 0; r < 8; ++r)
#pragma unroll
      for (int s = 0; s < 8; ++s) {
        float u = acc[r][s];
        float a = u / (1.0f + expf(-u));  // silu
        aBuf[(tm * 8 + r) * 132 + tn * 8 + s] = a;
      }
  }
  __syncthreads();

  // ---- KmT[q][m] = k(m-2q)  (overwrites Km region; Km dead after B)
  for (int idx = tid; idx < 64 * 128; idx += TPB) {
    int q = idx >> 7, m = idx & 127;
    KmT[q * 132 + m] = k1d[(m - 2 * q) & 127];
  }
  __syncthreads();

  // ---- Stage C: t2T[q][m] = dot(aBuf_row[m], KmT_row[q]), len 128.  Tiles 4q x 8m.
  // (writes into t1's region — t1 dead after B)
  {
    const int tq = tid >> 4, tm = tid & 15;  // q = tq*4.., m = tm*8..
    float acc[4][8];
#pragma unroll
    for (int qq = 0; qq < 4; ++qq)
#pragma unroll
      for (int r = 0; r < 8; ++r) acc[qq][r] = 0.0f;
    const float* Qr = KmT + tq * 4 * 132;
    const float* Ar = aBuf + tm * 8 * 132;
    for (int n = 0; n < 128; n += 4) {
      float4 qv[4], av[8];
#pragma unroll
      for (int qq = 0; qq < 4; ++qq) qv[qq] = *(const float4*)(Qr + qq * 132 + n);
#pragma unroll
      for (int r = 0; r < 8; ++r) av[r] = *(const float4*)(Ar + r * 132 + n);
#pragma unroll
      for (int qq = 0; qq < 4; ++qq)
#pragma unroll
        for (int r = 0; r < 8; ++r) acc[qq][r] += dot4(qv[qq], av[r]);
    }
#pragma unroll
    for (int qq = 0; qq < 4; ++qq)
#pragma unroll
      for (int r = 0; r < 8; ++r) t2T[(tq * 4 + qq) * 132 + tm * 8 + r] = acc[qq][r];
  }
  __syncthreads();

  // ---- Stage D: out[p][q] = 0.25 * dot(KmT_row[p], t2T_row[q]), len 128.  Tiles 4p x 4q.
  {
    const int tp = tid >> 4, tq = tid & 15;  // p = tp*4.., q = tq*4..
    float acc[4][4];
#pragma unroll
    for (int pp = 0; pp < 4; ++pp)
#pragma unroll
      for (int qq = 0; qq < 4; ++qq) acc[pp][qq] = 0.0f;
    const float* Pr = KmT + tp * 4 * 132;
    const float* Tr = t2T + tq * 4 * 132;
    for (int m = 0; m < 128; m += 4) {
      float4 pv[4], tv[4];
#pragma unroll
      for (int pp = 0; pp < 4; ++pp) pv[pp] = *(const float4*)(Pr + pp * 132 + m);
#pragma unroll
      for (int qq = 0; qq < 4; ++qq) tv[qq] = *(const float4*)(Tr + qq * 132 + m);
#pragma unroll
      for (int pp = 0; pp < 4; ++pp)
#pragma unroll
        for (int qq = 0; qq < 4; ++qq) acc[pp][qq] += dot4(pv[pp], tv[qq]);
    }
#pragma unroll
    for (int pp = 0; pp < 4; ++pp) {
      float4 o = make_float4(0.25f * acc[pp][0], 0.25f * acc[pp][1],
                             0.25f * acc[pp][2], 0.25f * acc[pp][3]);
      *(float4*)(out + (tp * 4 + pp) * 64 + tq * 4) = o;
    }
  }
}

extern "C" void kernel_launch(void* const* d_in, const int* in_sizes, int n_in,
                              void* d_out, int out_size, void* d_ws, size_t ws_size,
                              hipStream_t stream) {
  const float* x = (const float*)d_in[0];
  float* out = (float*)d_out;
  const int n_img = in_sizes[0] / 4096;  // B*C images of 64x64
  warped_kernel<<<dim3(n_img), dim3(TPB), 0, stream>>>(x, out);
}

// Round 2
// 118.954 us; speedup vs baseline: 3.8697x; 3.8697x over previous
//
#include <hip/hip_runtime.h>
#include <math.h>

#define TPB 256

typedef _Float16 f16x8 __attribute__((ext_vector_type(8)));
typedef float    f32x4 __attribute__((ext_vector_type(4)));

#define MFMA16(A, B, C) __builtin_amdgcn_mfma_f32_16x16x32_f16((A), (B), (C), 0, 0, 0)

// out = 0.25 * K^T * silu(K x K^T) * K per 64x64 image, K[m][i] = k1d[(m-2i) mod 128]
// (math verified on HW in round 1, absmax 1.6e-2 in fp32).
// MFMA chain with every stage Z_i = M * Z_{i-1}^T:
//   Z1 = K*x (128x64), Z2 = K*Z1^T = (K x K^T)^T (128x128), S = silu(Z2),
//   Z3 = KT*S^T = K^T a (64x128), Z4 = KT*Z3^T = 4*out^T (64x64).
// Row-major LDS store of each Z is exactly the next stage's B-operand layout:
//   B[k][n] = Z[n][k], frag = 8 consecutive k at fixed n -> ds_read_b128.
// Strides 72/136 u16: 16B-aligned rows, row-step*4 rotates banks by 8 (conflict-free
// C/D writes), frag-read aliasing <=2-way (free, m136).

__global__ __launch_bounds__(TPB) void warped_mfma(const float* __restrict__ xin,
                                                   float* __restrict__ outp, int nimg) {
  constexpr int SK = 72;   // stride (u16) for k-extent 64 buffers
  constexpr int SL = 136;  // stride (u16) for k-extent 128 buffers
  constexpr int SZ = 65;   // stride (f32) for output transpose buffer

  __shared__ __attribute__((aligned(16))) _Float16 Kf[128 * SK];   // K[m][k]
  __shared__ __attribute__((aligned(16))) _Float16 KTf[64 * SL];   // KT[q][k]
  __shared__ __attribute__((aligned(16))) _Float16 W0[64 * SK];    // x^T: W0[n][k]=x[k][n]
  __shared__ __attribute__((aligned(16))) _Float16 W1[128 * SK];   // Z1 row-major
  __shared__ __attribute__((aligned(16))) _Float16 W2[128 * SL];   // S  row-major
  __shared__ __attribute__((aligned(16))) _Float16 W3[64 * SL];    // Z3 row-major
  __shared__ __attribute__((aligned(16))) float Z4t[64 * SZ];      // Z4 row-major f32
  __shared__ float k1d[128];

  const int tid = threadIdx.x;
  const int w = tid >> 6;     // wave 0..3
  const int lane = tid & 63;
  const int lq = lane >> 4;   // quad 0..3
  const int ln = lane & 15;

  // ---- 1D half-band kernel (identical to verified round-1 code)
  if (tid < 128) {
    const int d = tid;
    float s = 1.0f + ((d & 1) ? 0.0f : ((d & 2) ? -1.0f : 1.0f));
    for (int f = 1; f <= 31; ++f) {
      int r = (f * d) & 127;
      s += 2.0f * cosf((float)r * 0.04908738521234052f /* pi/64 */);
    }
    k1d[d] = s * (1.0f / 64.0f);
  }
  __syncthreads();
  // ---- K tables (once per WG, amortized over nimg/grid images)
  for (int idx = tid; idx < 128 * 64; idx += TPB) {
    int m = idx >> 6, k = idx & 63;
    Kf[m * SK + k] = (_Float16)k1d[(m - 2 * k) & 127];
  }
  for (int idx = tid; idx < 64 * 128; idx += TPB) {
    int q = idx >> 7, k = idx & 127;
    KTf[q * SL + k] = (_Float16)k1d[(k - 2 * q) & 127];
  }
  // (barrier before first use is the stage-in barrier inside the loop)

  const f32x4 vzero = {0.0f, 0.0f, 0.0f, 0.0f};

  for (int img = blockIdx.x; img < nimg; img += gridDim.x) {
    const float* __restrict__ x = xin + (size_t)img * 4096;
    float* __restrict__ out = outp + (size_t)img * 4096;

    // ---- stage-in: x (f32, coalesced float4) -> W0[n][k] = x[k][n] as f16
#pragma unroll
    for (int rep = 0; rep < 4; ++rep) {
      int idx = tid + rep * TPB;  // float4 index 0..1023
      float4 v = ((const float4*)x)[idx];
      int i = idx >> 4, j0 = (idx & 15) << 2;  // x row i, cols j0..j0+3
      W0[(j0 + 0) * SK + i] = (_Float16)v.x;
      W0[(j0 + 1) * SK + i] = (_Float16)v.y;
      W0[(j0 + 2) * SK + i] = (_Float16)v.z;
      W0[(j0 + 3) * SK + i] = (_Float16)v.w;
    }
    __syncthreads();

    // ---- A-fragments of K for stages 1-2: wave w owns Z-rows [32w, 32w+32)
    f16x8 AK[2][2];
#pragma unroll
    for (int mt = 0; mt < 2; ++mt)
#pragma unroll
      for (int ks = 0; ks < 2; ++ks)
        AK[mt][ks] = *(const f16x8*)(Kf + ((2 * w + mt) * 16 + ln) * SK + ks * 32 + lq * 8);

    // ---- Stage 1: Z1 = K * x (128x64); wave: m-tiles {2w,2w+1}, n-tiles 0..3
    {
      f32x4 acc[2][4];
#pragma unroll
      for (int mt = 0; mt < 2; ++mt)
#pragma unroll
        for (int nt = 0; nt < 4; ++nt) acc[mt][nt] = vzero;
#pragma unroll
      for (int ks = 0; ks < 2; ++ks) {
        f16x8 B[4];
#pragma unroll
        for (int nt = 0; nt < 4; ++nt)
          B[nt] = *(const f16x8*)(W0 + (nt * 16 + ln) * SK + ks * 32 + lq * 8);
#pragma unroll
        for (int mt = 0; mt < 2; ++mt)
#pragma unroll
          for (int nt = 0; nt < 4; ++nt) acc[mt][nt] = MFMA16(AK[mt][ks], B[nt], acc[mt][nt]);
      }
#pragma unroll
      for (int mt = 0; mt < 2; ++mt)
#pragma unroll
        for (int nt = 0; nt < 4; ++nt)
#pragma unroll
          for (int r = 0; r < 4; ++r)
            W1[((2 * w + mt) * 16 + lq * 4 + r) * SK + nt * 16 + ln] = (_Float16)acc[mt][nt][r];
    }
    __syncthreads();

    // ---- Stage 2: Z2 = K * Z1^T (128x128) + silu; wave: m-tiles {2w,2w+1}, n-tiles 0..7
    {
      f32x4 acc[2][8];
#pragma unroll
      for (int mt = 0; mt < 2; ++mt)
#pragma unroll
        for (int nt = 0; nt < 8; ++nt) acc[mt][nt] = vzero;
#pragma unroll
      for (int ks = 0; ks < 2; ++ks) {
#pragma unroll
        for (int nt = 0; nt < 8; ++nt) {
          f16x8 B = *(const f16x8*)(W1 + (nt * 16 + ln) * SK + ks * 32 + lq * 8);
          acc[0][nt] = MFMA16(AK[0][ks], B, acc[0][nt]);
          acc[1][nt] = MFMA16(AK[1][ks], B, acc[1][nt]);
        }
      }
#pragma unroll
      for (int mt = 0; mt < 2; ++mt)
#pragma unroll
        for (int nt = 0; nt < 8; ++nt)
#pragma unroll
          for (int r = 0; r < 4; ++r) {
            float u = acc[mt][nt][r];
            float s = u * __builtin_amdgcn_rcpf(1.0f + __expf(-u));  // silu
            W2[((2 * w + mt) * 16 + lq * 4 + r) * SL + nt * 16 + ln] = (_Float16)s;
          }
    }
    __syncthreads();

    // ---- A-fragments of KT for stages 3-4: wave w owns Z-rows [16w, 16w+16)
    f16x8 AT[4];
#pragma unroll
    for (int ks = 0; ks < 4; ++ks)
      AT[ks] = *(const f16x8*)(KTf + (16 * w + ln) * SL + ks * 32 + lq * 8);

    // ---- Stage 3: Z3 = KT * S^T (64x128); wave: m-tile {w}, n-tiles 0..7
    {
      f32x4 acc[8];
#pragma unroll
      for (int nt = 0; nt < 8; ++nt) acc[nt] = vzero;
#pragma unroll
      for (int ks = 0; ks < 4; ++ks)
#pragma unroll
        for (int nt = 0; nt < 8; ++nt) {
          f16x8 B = *(const f16x8*)(W2 + (nt * 16 + ln) * SL + ks * 32 + lq * 8);
          acc[nt] = MFMA16(AT[ks], B, acc[nt]);
        }
#pragma unroll
      for (int nt = 0; nt < 8; ++nt)
#pragma unroll
        for (int r = 0; r < 4; ++r)
          W3[(16 * w + lq * 4 + r) * SL + nt * 16 + ln] = (_Float16)acc[nt][r];
    }
    __syncthreads();

    // ---- Stage 4: Z4 = KT * Z3^T (64x64) = 4*out^T; wave: m-tile {w}, n-tiles 0..3
    {
      f32x4 acc[4];
#pragma unroll
      for (int nt = 0; nt < 4; ++nt) acc[nt] = vzero;
#pragma unroll
      for (int ks = 0; ks < 4; ++ks)
#pragma unroll
        for (int nt = 0; nt < 4; ++nt) {
          f16x8 B = *(const f16x8*)(W3 + (nt * 16 + ln) * SL + ks * 32 + lq * 8);
          acc[nt] = MFMA16(AT[ks], B, acc[nt]);
        }
#pragma unroll
      for (int nt = 0; nt < 4; ++nt)
#pragma unroll
        for (int r = 0; r < 4; ++r)
          Z4t[(16 * w + lq * 4 + r) * SZ + nt * 16 + ln] = 0.25f * acc[nt][r];
    }
    __syncthreads();

    // ---- out[a][b] = 0.25*Z4[b][a]: transpose via LDS, coalesced float4 stores
#pragma unroll
    for (int rep = 0; rep < 4; ++rep) {
      int a = (tid >> 4) + rep * 16;
      int b0 = (tid & 15) << 2;
      float4 o;
      o.x = Z4t[(b0 + 0) * SZ + a];
      o.y = Z4t[(b0 + 1) * SZ + a];
      o.z = Z4t[(b0 + 2) * SZ + a];
      o.w = Z4t[(b0 + 3) * SZ + a];
      ((float4*)out)[(a * 64 + b0) >> 2] = o;
    }
    // next iteration's stage-in writes W0 (not in use) then barriers before reads
  }
}

extern "C" void kernel_launch(void* const* d_in, const int* in_sizes, int n_in,
                              void* d_out, int out_size, void* d_ws, size_t ws_size,
                              hipStream_t stream) {
  const float* x = (const float*)d_in[0];
  float* out = (float*)d_out;
  const int nimg = in_sizes[0] / 4096;  // B*C images of 64x64
  const int grid = nimg < 256 ? nimg : 256;
  warped_mfma<<<dim3(grid), dim3(TPB), 0, stream>>>(x, out, nimg);
}

// Round 3
// 100.334 us; speedup vs baseline: 4.5879x; 1.1856x over previous
//
#include <hip/hip_runtime.h>
#include <math.h>

#define TPB 256

typedef _Float16 f16x8 __attribute__((ext_vector_type(8)));
typedef float    f32x4 __attribute__((ext_vector_type(4)));

#define MFMA16(A, B, C) __builtin_amdgcn_mfma_f32_16x16x32_f16((A), (B), (C), 0, 0, 0)

// out = 0.25 * K^T * silu(K x K^T) * K per 64x64 image, K[m][i] = k1d[(m-2i) mod 128]
// (math + MFMA layouts verified on HW rounds 1-2, absmax 1.56e-2).
// Stages (every stage Z_i = M * Z_{i-1}^T, row-major LDS store == next B-operand layout):
//   Z1 = K*x (128x64), Z2 = K*Z1^T (128x128), S = silu(Z2),
//   Z3 = KT*S^T (64x128), Z4 = KT*Z3^T = 4*out^T (64x64).
// R3 changes vs R2: (a) K A-fragments computed into registers from k1d (no LDS K tables,
// -35.8 KB); (b) lifetime-aliased buffers: bufA = W0->W2->Z4t, bufB = W1->W3;
// LDS 53,760 B -> 3 WGs/CU (was 1 at 133 KB); (c) one image per WG, grid = nimg.

__global__ __launch_bounds__(TPB, 3) void warped_mfma(const float* __restrict__ xin,
                                                      float* __restrict__ outp) {
  constexpr int SK = 72;   // stride (u16), k-extent-64 buffers (W0, W1)
  constexpr int SL = 136;  // stride (u16), k-extent-128 buffers (W2, W3)
  constexpr int SZ = 65;   // stride (f32), output transpose buffer

  __shared__ __attribute__((aligned(16))) unsigned char bufA[128 * SL * 2];  // 34816 B
  __shared__ __attribute__((aligned(16))) unsigned char bufB[128 * SK * 2];  // 18432 B
  __shared__ float k1d[128];

  _Float16* const W0  = (_Float16*)bufA;  // [64][SK]  x^T, live stage-in -> S1
  _Float16* const W2  = (_Float16*)bufA;  // [128][SL] S, live S2 -> S3
  float*    const Z4t = (float*)bufA;     // [64][SZ]  Z4, live S4 -> writeout
  _Float16* const W1  = (_Float16*)bufB;  // [128][SK] Z1, live S1 -> S2
  _Float16* const W3  = (_Float16*)bufB;  // [64][SL]  Z3, live S3 -> S4

  const int tid = threadIdx.x;
  const int w = tid >> 6;    // wave 0..3
  const int lane = tid & 63;
  const int lq = lane >> 4;  // quad 0..3
  const int ln = lane & 15;

  const float* __restrict__ x = xin + (size_t)blockIdx.x * 4096;
  float* __restrict__ out     = outp + (size_t)blockIdx.x * 4096;

  // ---- 1D half-band kernel (verified): k(d) = (1/64)[1 + 2*sum cos(pi f d/64) + cos(pi d/2)]
  if (tid < 128) {
    const int d = tid;
    float s = 1.0f + ((d & 1) ? 0.0f : ((d & 2) ? -1.0f : 1.0f));
    for (int f = 1; f <= 31; ++f) {
      int r = (f * d) & 127;
      s += 2.0f * __cosf((float)r * 0.04908738521234052f /* pi/64 */);
    }
    k1d[d] = s * (1.0f / 64.0f);
  }
  __syncthreads();

  // ---- stage-in: x (f32, coalesced float4) -> W0[n][k] = x[k][n] as f16
#pragma unroll
  for (int rep = 0; rep < 4; ++rep) {
    int idx = tid + rep * TPB;  // float4 index 0..1023
    float4 v = ((const float4*)x)[idx];
    int i = idx >> 4, j0 = (idx & 15) << 2;  // x row i, cols j0..j0+3
    W0[(j0 + 0) * SK + i] = (_Float16)v.x;
    W0[(j0 + 1) * SK + i] = (_Float16)v.y;
    W0[(j0 + 2) * SK + i] = (_Float16)v.z;
    W0[(j0 + 3) * SK + i] = (_Float16)v.w;
  }

  // ---- A-fragments straight from k1d (registers; k1d ready after barrier above)
  // AK: rows of K, wave w owns Z-rows [32w, 32w+32). AT: rows of KT, wave w owns [16w,16w+16).
  f16x8 AK[2][2], AT[4];
#pragma unroll
  for (int mt = 0; mt < 2; ++mt)
#pragma unroll
    for (int ks = 0; ks < 2; ++ks) {
      const int m = (2 * w + mt) * 16 + ln;
      f16x8 a;
#pragma unroll
      for (int j = 0; j < 8; ++j) {
        int k = ks * 32 + lq * 8 + j;
        a[j] = (_Float16)k1d[(m - 2 * k) & 127];
      }
      AK[mt][ks] = a;
    }
#pragma unroll
  for (int ks = 0; ks < 4; ++ks) {
    const int q = 16 * w + ln;
    f16x8 a;
#pragma unroll
    for (int j = 0; j < 8; ++j) {
      int k = ks * 32 + lq * 8 + j;
      a[j] = (_Float16)k1d[(k - 2 * q) & 127];
    }
    AT[ks] = a;
  }
  __syncthreads();

  const f32x4 vzero = {0.0f, 0.0f, 0.0f, 0.0f};

  // ---- Stage 1: Z1 = K * x (128x64); wave: m-tiles {2w,2w+1}, n-tiles 0..3 -> W1
  {
    f32x4 acc[2][4];
#pragma unroll
    for (int mt = 0; mt < 2; ++mt)
#pragma unroll
      for (int nt = 0; nt < 4; ++nt) acc[mt][nt] = vzero;
#pragma unroll
    for (int ks = 0; ks < 2; ++ks) {
      f16x8 B[4];
#pragma unroll
      for (int nt = 0; nt < 4; ++nt)
        B[nt] = *(const f16x8*)(W0 + (nt * 16 + ln) * SK + ks * 32 + lq * 8);
#pragma unroll
      for (int mt = 0; mt < 2; ++mt)
#pragma unroll
        for (int nt = 0; nt < 4; ++nt) acc[mt][nt] = MFMA16(AK[mt][ks], B[nt], acc[mt][nt]);
    }
    __syncthreads();  // W0 reads done; W1 writes below race nothing (bufB idle)
#pragma unroll
    for (int mt = 0; mt < 2; ++mt)
#pragma unroll
      for (int nt = 0; nt < 4; ++nt)
#pragma unroll
        for (int r = 0; r < 4; ++r)
          W1[((2 * w + mt) * 16 + lq * 4 + r) * SK + nt * 16 + ln] = (_Float16)acc[mt][nt][r];
  }
  __syncthreads();

  // ---- Stage 2: Z2 = K * Z1^T (128x128) + silu -> W2 (bufA; W0 dead)
  {
    f32x4 acc[2][8];
#pragma unroll
    for (int mt = 0; mt < 2; ++mt)
#pragma unroll
      for (int nt = 0; nt < 8; ++nt) acc[mt][nt] = vzero;
#pragma unroll
    for (int ks = 0; ks < 2; ++ks) {
#pragma unroll
      for (int nt = 0; nt < 8; ++nt) {
        f16x8 B = *(const f16x8*)(W1 + (nt * 16 + ln) * SK + ks * 32 + lq * 8);
        acc[0][nt] = MFMA16(AK[0][ks], B, acc[0][nt]);
        acc[1][nt] = MFMA16(AK[1][ks], B, acc[1][nt]);
      }
    }
#pragma unroll
    for (int mt = 0; mt < 2; ++mt)
#pragma unroll
      for (int nt = 0; nt < 8; ++nt)
#pragma unroll
        for (int r = 0; r < 4; ++r) {
          float u = acc[mt][nt][r];
          float s = u * __builtin_amdgcn_rcpf(1.0f + __expf(-u));  // silu
          W2[((2 * w + mt) * 16 + lq * 4 + r) * SL + nt * 16 + ln] = (_Float16)s;
        }
  }
  __syncthreads();

  // ---- Stage 3: Z3 = KT * S^T (64x128); wave: m-tile {w}, n-tiles 0..7 -> W3 (bufB; W1 dead)
  {
    f32x4 acc[8];
#pragma unroll
    for (int nt = 0; nt < 8; ++nt) acc[nt] = vzero;
#pragma unroll
    for (int ks = 0; ks < 4; ++ks)
#pragma unroll
      for (int nt = 0; nt < 8; ++nt) {
        f16x8 B = *(const f16x8*)(W2 + (nt * 16 + ln) * SL + ks * 32 + lq * 8);
        acc[nt] = MFMA16(AT[ks], B, acc[nt]);
      }
    __syncthreads();  // W1 reads finished chipwide before W3 overwrite? (W1 dead since S2 barrier)
#pragma unroll
    for (int nt = 0; nt < 8; ++nt)
#pragma unroll
      for (int r = 0; r < 4; ++r)
        W3[(16 * w + lq * 4 + r) * SL + nt * 16 + ln] = (_Float16)acc[nt][r];
  }
  __syncthreads();

  // ---- Stage 4: Z4 = KT * Z3^T (64x64) = 4*out^T -> Z4t (bufA; W2 dead)
  {
    f32x4 acc[4];
#pragma unroll
    for (int nt = 0; nt < 4; ++nt) acc[nt] = vzero;
#pragma unroll
    for (int ks = 0; ks < 4; ++ks)
#pragma unroll
      for (int nt = 0; nt < 4; ++nt) {
        f16x8 B = *(const f16x8*)(W3 + (nt * 16 + ln) * SL + ks * 32 + lq * 8);
        acc[nt] = MFMA16(AT[ks], B, acc[nt]);
      }
    __syncthreads();  // W2 reads done before Z4t overwrites bufA
#pragma unroll
    for (int nt = 0; nt < 4; ++nt)
#pragma unroll
      for (int r = 0; r < 4; ++r)
        Z4t[(16 * w + lq * 4 + r) * SZ + nt * 16 + ln] = 0.25f * acc[nt][r];
  }
  __syncthreads();

  // ---- out[a][b] = 0.25*Z4[b][a]: transpose via LDS, coalesced float4 stores
#pragma unroll
  for (int rep = 0; rep < 4; ++rep) {
    int a = (tid >> 4) + rep * 16;
    int b0 = (tid & 15) << 2;
    float4 o;
    o.x = Z4t[(b0 + 0) * SZ + a];
    o.y = Z4t[(b0 + 1) * SZ + a];
    o.z = Z4t[(b0 + 2) * SZ + a];
    o.w = Z4t[(b0 + 3) * SZ + a];
    ((float4*)out)[(a * 64 + b0) >> 2] = o;
  }
}

extern "C" void kernel_launch(void* const* d_in, const int* in_sizes, int n_in,
                              void* d_out, int out_size, void* d_ws, size_t ws_size,
                              hipStream_t stream) {
  const float* x = (const float*)d_in[0];
  float* out = (float*)d_out;
  const int nimg = in_sizes[0] / 4096;  // B*C images of 64x64
  warped_mfma<<<dim3(nimg), dim3(TPB), 0, stream>>>(x, out);
}

// Round 6
// 96.539 us; speedup vs baseline: 4.7682x; 1.0393x over previous
//
#include <hip/hip_runtime.h>
#include <math.h>

#define TPB 256

typedef _Float16 f16x8 __attribute__((ext_vector_type(8)));
typedef float    f32x4 __attribute__((ext_vector_type(4)));

#define MFMA16(A, B, C) __builtin_amdgcn_mfma_f32_16x16x32_f16((A), (B), (C), 0, 0, 0)

// out = 0.25 * K^T * silu(K x K^T) * K per 64x64 image (math verified R1-R3, absmax 1.56e-2).
// R6: transpose-free MFMA chain. The consumer's B-read has a built-in transpose
// (B[k][n] = buf[n][k]); the producer's C/D layout stores D^T for free (acc[r] is 4
// consecutive elements of one COLUMN -> packed ds_write_b64 at buf[n][m0+lq*4]).
// Alternating data-as-A (right-mult) and data-as-B (left-mult) needs no DPP/scalar xpose:
//   buf0 = x               (row-major f16, packed stores)
//   S1: D1 = x*K^T   (A=buf0, B=AK)   -> buf1 = D1^T        [128][SA]
//   S2: D2 = K*buf1^T = K x K^T = u  (A=AK, B=buf1), silu  -> buf2 = silu(u)^T [128][SB]
//   S3: D3 = buf2*K = S^T K  (A=buf2, B=BT)                -> buf3 = D3^T = K^T S [64][SB]
//   S4: D4 = buf3*K = K^T S K = 4*out (A=buf3, B=BT)       -> buf4 = out^T f32 [64][SZ]
//   writeout: out[a][b] = buf4[b][a] (verified R3 pattern)
// K-register sharing: AK (rows (wk*4+t)*16+ln of K) serves S1's B and S2's A;
// BT (cols (wk*2+t)*16+ln, B[k][c]=K[k][c]) serves S3's and S4's B. 64 VGPRs total.
// All fragment layouts (A[m=lane&15][k=quad*8+j], B mirror, C/D col=lane&15,row=quad*4+reg)
// are HW-verified by passing R2/R3. LDS 53760 B -> 3 WGs/CU; 2 images/WG.

__device__ __forceinline__ void store4h(_Float16* p, float a0, float a1, float a2, float a3) {
  float2 q;
  q.x = __builtin_bit_cast(float, __builtin_amdgcn_cvt_pkrtz(a0, a1));  // low half = a0
  q.y = __builtin_bit_cast(float, __builtin_amdgcn_cvt_pkrtz(a2, a3));
  *(float2*)p = q;  // ds_write_b64
}

__global__ __launch_bounds__(TPB, 3) void warped_mfma(const float* __restrict__ xin,
                                                      float* __restrict__ outp, int nimg) {
  constexpr int SA = 72;   // u16 stride: buf0 [64][SA], buf1 [128][SA]
  constexpr int SB = 136;  // u16 stride: buf2 [128][SB], buf3 [64][SB]
  constexpr int SZ = 68;   // f32 stride: buf4 [64][SZ]

  __shared__ __attribute__((aligned(16))) unsigned char bufA[128 * SB * 2];  // 34816 B
  __shared__ __attribute__((aligned(16))) unsigned char bufB[128 * SA * 2];  // 18432 B
  __shared__ float k1d[128];

  _Float16* const buf0 = (_Float16*)bufA;  // [64][SA]   x, stage-in -> S1
  _Float16* const buf2 = (_Float16*)bufA;  // [128][SB]  silu(u)^T, S2 -> S3
  float*    const buf4 = (float*)bufA;     // [64][SZ]   out^T f32, S4 -> writeout
  _Float16* const buf1 = (_Float16*)bufB;  // [128][SA]  D1^T, S1 -> S2
  _Float16* const buf3 = (_Float16*)bufB;  // [64][SB]   K^T S, S3 -> S4

  const int tid = threadIdx.x;
  const int lane = tid & 63;
  const int w  = tid >> 6;  // wave 0..3
  const int wk = w >> 1;    // K-tile half (shared-frag axis)
  const int wd = w & 1;     // data-tile half
  const int lq = lane >> 4; // quad 0..3 (k dim of frags)
  const int ln = lane & 15; // m/n dim of frags

  // ---- 1D half-band kernel (verified R1): k(d) = (1/64)[1 + 2*sum cos(pi f d/64) + cos(pi d/2)]
  if (tid < 128) {
    const int d = tid;
    float s = 1.0f + ((d & 1) ? 0.0f : ((d & 2) ? -1.0f : 1.0f));
    for (int f = 1; f <= 31; ++f) {
      int r = (f * d) & 127;
      s += 2.0f * __cosf((float)r * 0.04908738521234052f /* pi/64 */);
    }
    k1d[d] = s * (1.0f / 64.0f);
  }
  __syncthreads();

  // ---- K fragments in registers (once per WG)
  // AK[t][ks]: K[a][k], a = (wk*4+t)*16+ln, k = ks*32+lq*8+j.  S1 B-operand & S2 A-operand.
  f16x8 AK[4][2];
#pragma unroll
  for (int t = 0; t < 4; ++t)
#pragma unroll
    for (int ks = 0; ks < 2; ++ks) {
      const int a = (wk * 4 + t) * 16 + ln;
      f16x8 f;
#pragma unroll
      for (int j = 0; j < 8; ++j) {
        int k = ks * 32 + lq * 8 + j;
        f[j] = (_Float16)k1d[(a - 2 * k) & 127];
      }
      AK[t][ks] = f;
    }
  // BT[t][ks]: B[k][c] = K[k][c], c = (wk*2+t)*16+ln, k = ks*32+lq*8+j.  S3 & S4 B-operand.
  f16x8 BT[2][4];
#pragma unroll
  for (int t = 0; t < 2; ++t)
#pragma unroll
    for (int ks = 0; ks < 4; ++ks) {
      const int c = (wk * 2 + t) * 16 + ln;
      f16x8 f;
#pragma unroll
      for (int j = 0; j < 8; ++j) {
        int k = ks * 32 + lq * 8 + j;
        f[j] = (_Float16)k1d[(k - 2 * c) & 127];
      }
      BT[t][ks] = f;
    }

  const f32x4 vzero = {0.0f, 0.0f, 0.0f, 0.0f};

  for (int img = blockIdx.x; img < nimg; img += gridDim.x) {
    const float* __restrict__ x = xin + (size_t)img * 4096;
    float* __restrict__ out     = outp + (size_t)img * 4096;

    // ---- stage-in: buf0[i][j] = x[i][j] as f16 (coalesced float4 reads, packed b64 writes)
#pragma unroll
    for (int rep = 0; rep < 4; ++rep) {
      int idx = rep * 256 + tid;  // float4 index 0..1023
      float4 v = ((const float4*)x)[idx];
      int i = idx >> 4, j0 = (idx & 15) << 2;
      store4h(buf0 + i * SA + j0, v.x, v.y, v.z, v.w);
    }
    __syncthreads();

    // ---- S1: D1 = x*K^T (64x128). m-tiles wd*2+{0,1}, n-tiles wk*4+{0..3}, ks 0..1.
    {
      f32x4 acc[2][4];
#pragma unroll
      for (int mtl = 0; mtl < 2; ++mtl)
#pragma unroll
        for (int ntl = 0; ntl < 4; ++ntl) acc[mtl][ntl] = vzero;
#pragma unroll
      for (int ks = 0; ks < 2; ++ks) {
        f16x8 Ad[2];
#pragma unroll
        for (int mtl = 0; mtl < 2; ++mtl)
          Ad[mtl] = *(const f16x8*)(buf0 + ((wd * 2 + mtl) * 16 + ln) * SA + ks * 32 + lq * 8);
#pragma unroll
        for (int mtl = 0; mtl < 2; ++mtl)
#pragma unroll
          for (int ntl = 0; ntl < 4; ++ntl)
            acc[mtl][ntl] = MFMA16(Ad[mtl], AK[ntl][ks], acc[mtl][ntl]);
      }
      // store D1^T: buf1[n][m] = D1[m][n]  (4 col-consecutive accs -> one b64)
#pragma unroll
      for (int mtl = 0; mtl < 2; ++mtl)
#pragma unroll
        for (int ntl = 0; ntl < 4; ++ntl) {
          int n0 = (wk * 4 + ntl) * 16, m0 = (wd * 2 + mtl) * 16;
          f32x4 a = acc[mtl][ntl];
          store4h(buf1 + (n0 + ln) * SA + m0 + lq * 4, a[0], a[1], a[2], a[3]);
        }
    }
    __syncthreads();

    // ---- S2: D2 = K*buf1^T = u (128x128), silu. m-tiles wk*4+{0..3}, n-tiles wd*4+{0..3}
    //      (two n-passes of 2), ks 0..1. Writes buf2 over buf0 (dead since S1-end barrier).
#pragma unroll
    for (int nh = 0; nh < 2; ++nh) {
      f32x4 acc[4][2];
#pragma unroll
      for (int mtl = 0; mtl < 4; ++mtl)
#pragma unroll
        for (int ntl = 0; ntl < 2; ++ntl) acc[mtl][ntl] = vzero;
#pragma unroll
      for (int ks = 0; ks < 2; ++ks) {
        f16x8 Bd[2];
#pragma unroll
        for (int ntl = 0; ntl < 2; ++ntl)
          Bd[ntl] =
              *(const f16x8*)(buf1 + ((wd * 4 + nh * 2 + ntl) * 16 + ln) * SA + ks * 32 + lq * 8);
#pragma unroll
        for (int mtl = 0; mtl < 4; ++mtl)
#pragma unroll
          for (int ntl = 0; ntl < 2; ++ntl)
            acc[mtl][ntl] = MFMA16(AK[mtl][ks], Bd[ntl], acc[mtl][ntl]);
      }
#pragma unroll
      for (int mtl = 0; mtl < 4; ++mtl)
#pragma unroll
        for (int ntl = 0; ntl < 2; ++ntl) {
          int n0 = (wd * 4 + nh * 2 + ntl) * 16, m0 = (wk * 4 + mtl) * 16;
          float s[4];
#pragma unroll
          for (int r = 0; r < 4; ++r) {
            float u = acc[mtl][ntl][r];
            s[r] = u * __builtin_amdgcn_rcpf(1.0f + __expf(-u));  // silu
          }
          store4h(buf2 + (n0 + ln) * SB + m0 + lq * 4, s[0], s[1], s[2], s[3]);
        }
    }
    __syncthreads();

    // ---- S3: D3 = buf2*K = S^T K (128x64). m-tiles wd*4+{0..3}, n-tiles wk*2+{0,1}, ks 0..3.
    //      Writes buf3 over buf1 (dead since S2-end barrier).
    {
      f32x4 acc[4][2];
#pragma unroll
      for (int mtl = 0; mtl < 4; ++mtl)
#pragma unroll
        for (int ntl = 0; ntl < 2; ++ntl) acc[mtl][ntl] = vzero;
#pragma unroll
      for (int ks = 0; ks < 4; ++ks) {
        f16x8 Ad[4];
#pragma unroll
        for (int mtl = 0; mtl < 4; ++mtl)
          Ad[mtl] = *(const f16x8*)(buf2 + ((wd * 4 + mtl) * 16 + ln) * SB + ks * 32 + lq * 8);
#pragma unroll
        for (int mtl = 0; mtl < 4; ++mtl)
#pragma unroll
          for (int ntl = 0; ntl < 2; ++ntl)
            acc[mtl][ntl] = MFMA16(Ad[mtl], BT[ntl][ks], acc[mtl][ntl]);
      }
#pragma unroll
      for (int mtl = 0; mtl < 4; ++mtl)
#pragma unroll
        for (int ntl = 0; ntl < 2; ++ntl) {
          int n0 = (wk * 2 + ntl) * 16, m0 = (wd * 4 + mtl) * 16;
          f32x4 a = acc[mtl][ntl];
          store4h(buf3 + (n0 + ln) * SB + m0 + lq * 4, a[0], a[1], a[2], a[3]);
        }
    }
    __syncthreads();

    // ---- S4: D4 = buf3*K = 4*out (64x64). m-tiles wd*2+{0,1}, n-tiles wk*2+{0,1}, ks 0..3.
    //      Writes buf4 over buf2 (dead since S3-end barrier). f32 b128 col-stores.
    {
      f32x4 acc[2][2];
#pragma unroll
      for (int mtl = 0; mtl < 2; ++mtl)
#pragma unroll
        for (int ntl = 0; ntl < 2; ++ntl) acc[mtl][ntl] = vzero;
#pragma unroll
      for (int ks = 0; ks < 4; ++ks) {
        f16x8 Ad[2];
#pragma unroll
        for (int mtl = 0; mtl < 2; ++mtl)
          Ad[mtl] = *(const f16x8*)(buf3 + ((wd * 2 + mtl) * 16 + ln) * SB + ks * 32 + lq * 8);
#pragma unroll
        for (int mtl = 0; mtl < 2; ++mtl)
#pragma unroll
          for (int ntl = 0; ntl < 2; ++ntl)
            acc[mtl][ntl] = MFMA16(Ad[mtl], BT[ntl][ks], acc[mtl][ntl]);
      }
#pragma unroll
      for (int mtl = 0; mtl < 2; ++mtl)
#pragma unroll
        for (int ntl = 0; ntl < 2; ++ntl) {
          int n0 = (wk * 2 + ntl) * 16, m0 = (wd * 2 + mtl) * 16;
          f32x4 o = acc[mtl][ntl];
          o[0] *= 0.25f; o[1] *= 0.25f; o[2] *= 0.25f; o[3] *= 0.25f;
          *(f32x4*)(buf4 + (n0 + ln) * SZ + m0 + lq * 4) = o;  // buf4[n][m] = out^T
        }
    }
    __syncthreads();

    // ---- writeout: out[a][b] = buf4[b][a], coalesced float4 stores (verified R3 pattern)
#pragma unroll
    for (int rep = 0; rep < 4; ++rep) {
      int a = (tid >> 4) + rep * 16;
      int b0 = (tid & 15) << 2;
      float4 o;
      o.x = buf4[(b0 + 0) * SZ + a];
      o.y = buf4[(b0 + 1) * SZ + a];
      o.z = buf4[(b0 + 2) * SZ + a];
      o.w = buf4[(b0 + 3) * SZ + a];
      ((float4*)out)[(a * 64 + b0) >> 2] = o;
    }
    __syncthreads();  // buf4 reads done before next image's stage-in overwrites bufA
  }
}

extern "C" void kernel_launch(void* const* d_in, const int* in_sizes, int n_in,
                              void* d_out, int out_size, void* d_ws, size_t ws_size,
                              hipStream_t stream) {
  const float* x = (const float*)d_in[0];
  float* out = (float*)d_out;
  const int nimg = in_sizes[0] / 4096;  // B*C images of 64x64
  const int grid = (nimg + 1) / 2;      // 2 images per WG
  warped_mfma<<<dim3(grid), dim3(TPB), 0, stream>>>(x, out, nimg);
}